// Round 7
// baseline (436.296 us; speedup 1.0000x reference)
//
#include <hip/hip_runtime.h>
#include <math.h>
#include <stdint.h>

#define HH 2048
#define WW 2048
#define NB 256           // threads per block (4 waves)
#define GRID 256         // 1 block per CU: co-residency for the handshake
#define NWAVES (GRID * 4)
#define NWW 1020         // worker staging waves (blocks 1..255 x 4)
#define CTRL_INTS 2048   // 8 KB control region, zeroed by memset each call

// ctrl int layout:
//   [0..1]  epoch packet (uint64): tag(100+k)<<40 | e<<20 | s<<4 | valid<<1
//   grp(st,g)  at 16 + st*128 + g*16   (st: 9=phase-A, 8..0=band stages; g=0..7)
//   root(st)   at 16 + 1280 + st*16

// ---------- wave reductions (no LDS, no barriers) ----------
__device__ __forceinline__ float wave_fmax(float v) {
#pragma unroll
  for (int m = 1; m < 64; m <<= 1) v = fmaxf(v, __shfl_xor(v, m, 64));
  return v;
}
__device__ __forceinline__ float wave_fsum(float v) {
#pragma unroll
  for (int m = 1; m < 64; m <<= 1) v += __shfl_xor(v, m, 64);
  return v;
}

// ---------- per-row softmax partial, ONE wave, zero barriers ----------
// (M, z, sx): M = max(100*v), z = sum(exp(100*v-M)), sx = sum(exp*col).
// Verbatim from R5 (verified absmax 0.0) — keep bit-identical.
__device__ float4 wave_row_partial(const float* __restrict__ rowp) {
  const int lane = threadIdx.x & 63;
  const float4* r4 = (const float4*)rowp;
  float d[32];
  float m = -INFINITY;
#pragma unroll
  for (int p = 0; p < 8; ++p) {
    float4 v = r4[lane + 64 * p];
    d[4 * p + 0] = v.x * 100.0f;  // BETA
    d[4 * p + 1] = v.y * 100.0f;
    d[4 * p + 2] = v.z * 100.0f;
    d[4 * p + 3] = v.w * 100.0f;
    m = fmaxf(m, fmaxf(fmaxf(d[4 * p], d[4 * p + 1]), fmaxf(d[4 * p + 2], d[4 * p + 3])));
  }
  float M = wave_fmax(m);
  float z = 0.0f, sx = 0.0f;
#pragma unroll
  for (int p = 0; p < 8; ++p) {
    float c0 = (float)(4 * (lane + 64 * p));
#pragma unroll
    for (int k = 0; k < 4; ++k) {
      float e = expf(d[4 * p + k] - M);
      z += e;
      sx += e * (c0 + (float)k);
    }
  }
  z = wave_fsum(z);
  sx = wave_fsum(sx);
  return make_float4(M, z, sx, 0.0f);
}

// ---------- block (256-thread) reductions, R5-identical ----------
__device__ float block_fmax(float v) {
  __shared__ float s[4];
  v = wave_fmax(v);
  __syncthreads();
  if ((threadIdx.x & 63) == 0) s[threadIdx.x >> 6] = v;
  __syncthreads();
  return fmaxf(fmaxf(s[0], s[1]), fmaxf(s[2], s[3]));
}
__device__ void block_fsum3(float& a, float& b, float& c) {
  __shared__ float sa[4], sb[4], sc[4];
  a = wave_fsum(a); b = wave_fsum(b); c = wave_fsum(c);
  __syncthreads();
  if ((threadIdx.x & 63) == 0) {
    int w = threadIdx.x >> 6;
    sa[w] = a; sb[w] = b; sc[w] = c;
  }
  __syncthreads();
  a = (sa[0] + sa[1]) + (sa[2] + sa[3]);
  b = (sb[0] + sb[1]) + (sb[2] + sb[3]);
  c = (sc[0] + sc[1]) + (sc[2] + sc[3]);
}

// Merge per-row partials arr[r], r in [s,e] (sy weight = r). Stride NB = R5-identical.
__device__ void merge_partials(const float4* __restrict__ arr, int s, int e,
                               float& M, float& Z, float& SX, float& SY) {
  float m = -INFINITY;
  for (int r = s + (int)threadIdx.x; r <= e; r += NB) m = fmaxf(m, arr[r].x);
  M = block_fmax(m);
  float z = 0.0f, sx = 0.0f, sy = 0.0f;
  for (int r = s + (int)threadIdx.x; r <= e; r += NB) {
    float4 p = arr[r];
    float w = expf(p.x - M);
    z  += w * p.y;
    sx += w * p.z;
    sy += w * p.y * (float)r;
  }
  block_fsum3(z, sx, sy);
  Z = z; SX = sx; SY = sy;
}

// Analytic out-of-band complement (masked elements are exactly 0), then divide.
__device__ void finalize2(float M, float Z, float SX, float SY, int s, int e,
                          bool valid, float& ax, float& ay) {
  int nin = valid ? (e - s + 1) : 0;
  int nout = HH - nin;
  if (nout > 0) {
    float M2 = fmaxf(M, 0.0f);
    float wi = (M == M2) ? 1.0f : expf(M - M2);
    float wo = (M2 == 0.0f) ? 1.0f : expf(-M2);
    Z *= wi; SX *= wi; SY *= wi;
    float nout_e = (float)nout * (float)WW;
    float sox = (float)nout * 2096128.0f;
    float sinr = valid ? (float)(((long)(s + e) * (e - s + 1)) / 2) : 0.0f;
    float soy = (2096128.0f - sinr) * 2048.0f;
    Z  += wo * nout_e;
    SX += wo * sox;
    SY += wo * soy;
  }
  ax = SX / Z;
  ay = SY / Z;
}

// ---------- handshake primitives ----------
// All-threads entry; syncthreads ensures all waves' stores complete (vmcnt drained
// at barrier), then thread 0's threadfence (buffer_wbl2+inv, cache-wide) publishes
// them device-wide before the device-scope check-in atomic. (R1-validated pattern.)
__device__ void checkin(int* ctrl, int st) {
  __syncthreads();
  if (threadIdx.x == 0) {
    __threadfence();
    int g = (int)blockIdx.x & 7;
    int old = atomicAdd(ctrl + 16 + st * 128 + g * 16, 1);
    if (old == 31) atomicAdd(ctrl + 16 + 1280 + st * 16, 32);  // 32 blocks/group
  }
}

__device__ void leader_wait(int* ctrl, int st) {
  if (threadIdx.x == 0) {
    while (__hip_atomic_load(ctrl + 16 + 1280 + st * 16, __ATOMIC_ACQUIRE,
                             __HIP_MEMORY_SCOPE_AGENT) < GRID)
      __builtin_amdgcn_s_sleep(1);
    __threadfence();   // invalidate L1/L2 before reading workers' partials
  }
  __syncthreads();
}

__global__ __launch_bounds__(NB) void k_fused(const float* __restrict__ heat,
                                              float* ws, float* __restrict__ out) {
  int* ctrl = (int*)ws;
  uint64_t* ep = (uint64_t*)ws;
  float4* F  = (float4*)(ws + CTRL_INTS);
  float4* B0 = F + 4096;
  float4* B1 = B0 + HH;
  const int tid = (int)threadIdx.x;
  const int wv  = tid >> 6;

  // -------- Phase A: stage ch9/10 row partials (all 256 blocks) --------
  {
    const int wid = (int)blockIdx.x * 4 + wv;           // 0..1023
    for (int rr = wid; rr < 2 * HH; rr += NWAVES) {
      int ch = 9 + (rr >> 11), r = rr & (HH - 1);
      float4 t = wave_row_partial(heat + ((size_t)ch * HH + r) * WW);
      if ((tid & 63) == 0) F[rr] = t;
    }
  }
  checkin(ctrl, 9);

  if (blockIdx.x == 0) {
    // ---------------- LEADER ----------------
    __shared__ float s_out[22];
    leader_wait(ctrl, 9);
    float M, Z, SX, SY, ax, ay;
    merge_partials(F, 0, HH - 1, M, Z, SX, SY);
    finalize2(M, Z, SX, SY, 0, HH - 1, true, ax, ay);
    float ax9 = ax, ay9 = ay;
    merge_partials(F + HH, 0, HH - 1, M, Z, SX, SY);
    finalize2(M, Z, SX, SY, 0, HH - 1, true, ax, ay);
    if (tid == 0) { s_out[18] = ax9; s_out[19] = ay9; s_out[20] = ax; s_out[21] = ay; }

    float y1 = ay9, y2 = ay;                 // out[9].y, out[10].y
    float dis = ay - ay9, dsum = 0.0f, dnum = 0.0f;

    for (int i = 8; i >= 0; --i) {
      // band + dis-state update (uniform across block-0 threads; R5-identical)
      float last_y = floorf(y1);
      float tmp = ceilf(y2 - y1);
      bool cond = fabsf(tmp - dis) > 0.35f * dis;
      if (cond) { dsum += tmp; dnum += 1.0f; dis = dsum / fmaxf(dnum, 1.0f); }
      float start_raw = last_y - 1.8f * dis;
      float end_f   = rintf(start_raw + 1.8f * dis);   // jnp.round = rint
      float start_f = rintf(start_raw);
      int s2 = (int)fmaxf(start_f, 0.0f);
      int e2 = (int)fminf(end_f, (float)(HH - 1));
      bool bvalid = (s2 <= e2) && (end_f >= 0.0f) && (start_f <= (float)(HH - 1));

      if (tid == 0) {
        uint64_t pkt = ((uint64_t)(100 + i) << 40) | ((uint64_t)(uint32_t)e2 << 20)
                     | ((uint64_t)(uint32_t)s2 << 4) | (bvalid ? 2u : 0u);
        __hip_atomic_store(ep, pkt, __ATOMIC_RELEASE, __HIP_MEMORY_SCOPE_AGENT);
      }
      checkin(ctrl, i);          // leader stages nothing for bands (serial path)
      leader_wait(ctrl, i);

      M = -INFINITY; Z = 0.0f; SX = 0.0f; SY = 0.0f;
      const float4* Bc = (i & 1) ? B1 : B0;
      if (bvalid) merge_partials(Bc, s2, e2, M, Z, SX, SY);   // uniform branch
      finalize2(M, Z, SX, SY, s2, e2, bvalid, ax, ay);
      if (tid == 0) { s_out[2 * i] = ax; s_out[2 * i + 1] = ay; }
      y2 = y1; y1 = ay;
    }
    __syncthreads();
    if (tid < 22) out[tid] = s_out[tid];
  } else {
    // ---------------- WORKERS ----------------
    __shared__ uint64_t sp;
    const int wid = ((int)blockIdx.x - 1) * 4 + wv;     // 0..1019
    for (int k = 8; k >= 0; --k) {
      if (tid == 0) {
        uint64_t p;
        while (((p = __hip_atomic_load(ep, __ATOMIC_ACQUIRE,
                                       __HIP_MEMORY_SCOPE_AGENT)) >> 40)
               != (uint64_t)(100 + k))
          __builtin_amdgcn_s_sleep(1);
        sp = p;
      }
      __syncthreads();
      uint64_t p = sp;
      bool valid = (p & 2u) != 0;
      int s2 = (int)((p >> 4)  & 0xFFFF);
      int e2 = (int)((p >> 20) & 0xFFFF);
      float4* Bcur = (k & 1) ? B1 : B0;
      if (valid) {
        for (int r = s2 + wid; r <= e2; r += NWW) {
          float4 t = wave_row_partial(heat + ((size_t)k * HH + r) * WW);
          if ((tid & 63) == 0) Bcur[r] = t;
        }
      }
      checkin(ctrl, k);          // includes the syncthreads (WAR guard for sp)
    }
  }
}

extern "C" void kernel_launch(void* const* d_in, const int* in_sizes, int n_in,
                              void* d_out, int out_size, void* d_ws, size_t ws_size,
                              hipStream_t stream) {
  const float* heat = (const float*)d_in[0];
  float* out = (float*)d_out;
  float* ws = (float*)d_ws;
  hipMemsetAsync(d_ws, 0, CTRL_INTS * sizeof(int), stream);   // zero handshake state
  hipLaunchKernelGGL(k_fused, dim3(GRID), dim3(NB), 0, stream, heat, ws, out);
}